// Round 7
// baseline (6814.855 us; speedup 1.0000x reference)
//
#include <hip/hip_runtime.h>

#define NB 4096   // batch
#define NH 1024   // hidden
#define NE 512    // embedding dim
#define NV 23     // vocab
#define NT 64     // seq len
#define NL 144    // latent+cond
#define PADV 21
#define SOSV 22

typedef unsigned short u16;
typedef __attribute__((ext_vector_type(4))) float f32x4;
typedef __attribute__((ext_vector_type(8))) __bf16 bf16x8;
typedef __attribute__((ext_vector_type(8))) unsigned short u16x8;

__device__ __forceinline__ u16 f2bf(float x) {
  unsigned u = __float_as_uint(x);
  u += 0x7FFFu + ((u >> 16) & 1u);   // RNE to bf16
  return (u16)(u >> 16);
}
__device__ __forceinline__ float bf2f(u16 h) {
  return __uint_as_float(((unsigned)h) << 16);
}

// h image layout: [mt=m>>7][ks=j>>5][q=(j>>3)&3][row=m&127][e=j&7]
__device__ __forceinline__ size_t hidx(int m, int j) {
  return ((size_t)(((m >> 7) * 32 + (j >> 5)) * 4 + ((j >> 3) & 3)) * 1024)
         + (size_t)((m & 127) * 8) + (j & 7);
}

// ---------------------------------------------------------------------------
// prep: split W_hh into bf16 hi/lo images, zero c, SOS tokens.
// W image: [jt=j>>5][ks=k>>5][q=(k>>3)&3][row=g*32+(j&31)][e=k&7]
__global__ void prep_kernel(const float* __restrict__ Whh, u16* __restrict__ Whi,
                            u16* __restrict__ Wlo, float* __restrict__ c,
                            int* __restrict__ tok) {
  int i = blockIdx.x * 256 + threadIdx.x;   // 4M threads = 4*NH*NH = NB*NH
  float wv = Whh[i];
  u16 hi = f2bf(wv);
  u16 lo = f2bf(wv - bf2f(hi));
  const int nw = i >> 10, k = i & 1023;
  const int g = nw >> 10, jcol = nw & 1023;
  const int jt = jcol >> 5, jl = jcol & 31;
  const int row = (g << 5) + jl;
  const size_t oi = ((size_t)((jt * 32 + (k >> 5)) * 4 + ((k >> 3) & 3)) * 1024)
                    + (size_t)(row * 8) + (k & 7);
  Whi[oi] = hi;
  Wlo[oi] = lo;
  c[i] = 0.0f;
  if (i < NB) tok[i] = SOSV;
}

// ---------------------------------------------------------------------------
__global__ void exw_kernel(const float* __restrict__ emb, const float* __restrict__ Wih,
                           const float* __restrict__ bih, const float* __restrict__ bhh,
                           float* __restrict__ ExW) {
  __shared__ float Es[NE];
  const int v = blockIdx.y;
  const int n = blockIdx.x * 256 + threadIdx.x;
  for (int k = threadIdx.x; k < NE; k += 256)
    Es[k] = (v == PADV) ? 0.0f : emb[v * NE + k];
  __syncthreads();
  float s = bih[n] + bhh[n];
  const float* wr = Wih + (long)n * NE;
  for (int k = 0; k < NE; ++k) s = fmaf(Es[k], wr[k], s);
  ExW[v * (4 * NH) + n] = s;
}

// ---------------------------------------------------------------------------
__global__ void h0_kernel(const float* __restrict__ z, const float* __restrict__ cnd,
                          const float* __restrict__ Wlh, const float* __restrict__ blh,
                          u16* __restrict__ hhi, u16* __restrict__ hlo) {
  __shared__ float zc[8][NL];
  const int b0 = blockIdx.y * 8;
  const int j = blockIdx.x * 256 + threadIdx.x;
  for (int idx = threadIdx.x; idx < 8 * NL; idx += 256) {
    int bi = idx / NL, k = idx % NL;
    zc[bi][k] = (k < 128) ? z[(long)(b0 + bi) * 128 + k]
                          : cnd[(long)(b0 + bi) * 16 + (k - 128)];
  }
  __syncthreads();
  float acc[8];
  const float bj = blh[j];
#pragma unroll
  for (int bi = 0; bi < 8; ++bi) acc[bi] = bj;
  const float* wr = Wlh + (long)j * NL;
  for (int k = 0; k < NL; ++k) {
    float wv = wr[k];
#pragma unroll
    for (int bi = 0; bi < 8; ++bi) acc[bi] = fmaf(wv, zc[bi][k], acc[bi]);
  }
#pragma unroll
  for (int bi = 0; bi < 8; ++bi) {
    size_t idx = hidx(b0 + bi, j);
    u16 hi = f2bf(acc[bi]);
    hhi[idx] = hi;
    hlo[idx] = f2bf(acc[bi] - bf2f(hi));
  }
}

// ---------------------------------------------------------------------------
__device__ __forceinline__ void gll(const u16* src, u16* dst) {
  __builtin_amdgcn_global_load_lds(
      (const __attribute__((address_space(1))) void*)src,
      (__attribute__((address_space(3))) void*)dst, 16, 0, 0);
}

// Fused gates GEMM (split-bf16, 3 MFMA products, 16x16x32) + LSTM cell epilogue.
// 256 thr (4 waves = 2 wm x 2 wn). Tile: 128 m x (32 j x 4 g). BK=32.
// 64 KB double-buffered LDS -> 2 blocks/CU: cross-block phase diversity hides
// the LDS read/stage phase under the other block's MFMA phase (m114 mechanism).
// Wave w stages matrix w (Ahi/Alo/Bhi/Blo), 8 contiguous-1KB gll per lane.
__global__ __launch_bounds__(256, 2)
void gates_cell_kernel(const u16* __restrict__ Whi, const u16* __restrict__ Wlo,
                       const u16* __restrict__ hhi_in, const u16* __restrict__ hlo_in,
                       const float* __restrict__ ExW, const int* __restrict__ tok,
                       float* __restrict__ c, u16* __restrict__ hhi_out,
                       u16* __restrict__ hlo_out) {
  __shared__ u16 lds[32768];   // 64 KB: [4 mats][2 dbuf][4 q][128 rows][8e]

  const int bid = blockIdx.x;             // 1024 blocks = 32 mt x 32 jt
  const int xcd = bid & 7;                // dispatch round-robins XCDs
  const int local = bid >> 3;             // 0..127
  const int jt = (xcd << 2) | (local & 3);   // XCD owns 4 jt slices (W L2-resident)
  const int mt = local >> 2;              // 0..31
  const int m0 = mt << 7;
  const int j0 = jt << 5;

  const int tid = threadIdx.x;
  const int w = tid >> 6, l = tid & 63;
  const int wm = w >> 1, wn = w & 1;      // wave tile: 64 m x (16 j x 4 g)
  const int q = l >> 4, rL = l & 15;

  // staging: wave w owns mat w (0 Ahi, 1 Alo, 2 Bhi, 3 Blo)
  const u16* simg = (w == 0) ? hhi_in : (w == 1) ? hlo_in : (w == 2) ? Whi : Wlo;
  const size_t sbase = ((w < 2) ? ((size_t)mt * 131072) : ((size_t)jt * 131072))
                       + (size_t)l * 8;
  const u16* sit = simg + sbase;                  // + ks*4096 per K-step
  u16* dwave = (u16*)lds + w * 8192 + l * 8;      // + buf*4096 + i*512

  // prefetch greedy tokens for this thread's 16 output rows
  int tkv[16];
#pragma unroll
  for (int mi = 0; mi < 4; ++mi)
#pragma unroll
    for (int r = 0; r < 4; ++r)
      tkv[mi * 4 + r] = tok[m0 + wm * 64 + mi * 16 + q * 4 + r];

  f32x4 acc[4][4];   // [mi][g]
#pragma unroll
  for (int mi = 0; mi < 4; ++mi)
#pragma unroll
    for (int g = 0; g < 4; ++g) acc[mi][g] = (f32x4){0.f, 0.f, 0.f, 0.f};

  // prologue: stage ks=0 -> buf0
#pragma unroll
  for (int i = 0; i < 8; ++i) gll(sit + i * 512, dwave + i * 512);
  __syncthreads();

  for (int ks = 0; ks < 32; ++ks) {
    const int buf = ks & 1;
    if (ks < 31) {
      const u16* src = sit + (size_t)(ks + 1) * 4096;
      u16* dst = dwave + (buf ^ 1) * 4096;
#pragma unroll
      for (int i = 0; i < 8; ++i) gll(src + i * 512, dst + i * 512);
    }
    const u16* base = lds + buf * 4096 + q * 1024;
    bf16x8 ah[4], al[4];
#pragma unroll
    for (int mi = 0; mi < 4; ++mi) {
      const int ao = (wm * 64 + mi * 16 + rL) * 8;
      ah[mi] = *reinterpret_cast<const bf16x8*>(base + ao);
      al[mi] = *reinterpret_cast<const bf16x8*>(base + 8192 + ao);
    }
#pragma unroll
    for (int g = 0; g < 4; ++g) {
      const int bo = (g * 32 + wn * 16 + rL) * 8;
      const bf16x8 bh = *reinterpret_cast<const bf16x8*>(base + 16384 + bo);
      const bf16x8 bl = *reinterpret_cast<const bf16x8*>(base + 24576 + bo);
#pragma unroll
      for (int mi = 0; mi < 4; ++mi)
        acc[mi][g] = __builtin_amdgcn_mfma_f32_16x16x32_bf16(ah[mi], bh, acc[mi][g], 0, 0, 0);
#pragma unroll
      for (int mi = 0; mi < 4; ++mi)
        acc[mi][g] = __builtin_amdgcn_mfma_f32_16x16x32_bf16(ah[mi], bl, acc[mi][g], 0, 0, 0);
#pragma unroll
      for (int mi = 0; mi < 4; ++mi)
        acc[mi][g] = __builtin_amdgcn_mfma_f32_16x16x32_bf16(al[mi], bh, acc[mi][g], 0, 0, 0);
    }
    __syncthreads();   // drains stage (vmcnt0) + guards dbuf reuse
  }

  // epilogue: + ExW[token], LSTM cell (fp32), write h hi/lo in image layout.
  // acc[mi][g][r] are the 4 gates of ONE (m, j) cell: j = j0 + wn*16 + rL.
  const int j = j0 + wn * 16 + rL;
#pragma unroll
  for (int mi = 0; mi < 4; ++mi) {
#pragma unroll
    for (int r = 0; r < 4; ++r) {
      const int m = m0 + wm * 64 + mi * 16 + q * 4 + r;   // C row = (lane>>4)*4 + reg
      const float* exr = ExW + (size_t)tkv[mi * 4 + r] * 4096;
      const float gi = acc[mi][0][r] + exr[j];
      const float gf = acc[mi][1][r] + exr[NH + j];
      const float gg = acc[mi][2][r] + exr[2 * NH + j];
      const float go = acc[mi][3][r] + exr[3 * NH + j];
      const float i_ = 1.0f / (1.0f + expf(-gi));
      const float f_ = 1.0f / (1.0f + expf(-gf));
      const float g_ = tanhf(gg);
      const float o_ = 1.0f / (1.0f + expf(-go));
      const size_t cidx = (size_t)m * NH + j;
      const float cn = f_ * c[cidx] + i_ * g_;
      c[cidx] = cn;
      const float hn = o_ * tanhf(cn);
      const u16 hi = f2bf(hn);
      const size_t oidx = hidx(m, j);
      hhi_out[oidx] = hi;
      hlo_out[oidx] = f2bf(hn - bf2f(hi));
    }
  }
}

// ---------------------------------------------------------------------------
// logits = h @ W_out^T + b_out ; 8 batch rows per block (amortize W_out reads).
__global__ __launch_bounds__(256)
void logits_kernel(const u16* __restrict__ hhi, const u16* __restrict__ hlo,
                   const float* __restrict__ Wout, const float* __restrict__ bout,
                   float* __restrict__ out, int* __restrict__ tok, int t) {
  __shared__ float hs[8][NH];
  __shared__ float part[8][24][8];
  __shared__ float lg[8][24];
  const int b0 = blockIdx.x * 8;
  const int tid = threadIdx.x;
  for (int ci = tid; ci < 1024; ci += 256) {
    const int bi = ci >> 7, cj = ci & 127;
    const int m = b0 + bi;
    const int ks = cj >> 2, qq = cj & 3;
    const size_t base = ((size_t)(((m >> 7) * 32 + ks) * 4 + qq) * 1024)
                        + (size_t)((m & 127) * 8);
    const u16x8 vh = *reinterpret_cast<const u16x8*>(hhi + base);
    const u16x8 vl = *reinterpret_cast<const u16x8*>(hlo + base);
    const int kb = ks * 32 + qq * 8;
#pragma unroll
    for (int e = 0; e < 8; ++e) hs[bi][kb + e] = bf2f(vh[e]) + bf2f(vl[e]);
  }
  __syncthreads();
  const int v = tid & 31, kc = tid >> 5;
  if (v < NV) {
    float s[8];
#pragma unroll
    for (int bi = 0; bi < 8; ++bi) s[bi] = 0.f;
    const float* wr = Wout + (long)v * NH + kc * 128;
    const int kb = kc * 128;
    for (int k = 0; k < 128; ++k) {
      float wv = wr[k];
#pragma unroll
      for (int bi = 0; bi < 8; ++bi) s[bi] = fmaf(wv, hs[bi][kb + k], s[bi]);
    }
#pragma unroll
    for (int bi = 0; bi < 8; ++bi) part[kc][v][bi] = s[bi];
  }
  __syncthreads();
  if (tid < NV * 8) {
    const int vv = tid >> 3, bi = tid & 7;
    float s = bout[vv];
#pragma unroll
    for (int k = 0; k < 8; ++k) s += part[k][vv][bi];
    lg[bi][vv] = s;
    out[((long)(b0 + bi) * NT + t) * NV + vv] = s;
  }
  __syncthreads();
  if (tid < 8) {
    float best = lg[tid][0];
    int bv = 0;
    for (int vv = 1; vv < NV; ++vv) {
      float x = lg[tid][vv];
      if (x > best) { best = x; bv = vv; }   // strict > : first-max like np.argmax
    }
    tok[b0 + tid] = bv;
  }
}

// ---------------------------------------------------------------------------
extern "C" void kernel_launch(void* const* d_in, const int* in_sizes, int n_in,
                              void* d_out, int out_size, void* d_ws, size_t ws_size,
                              hipStream_t stream) {
  const float* z    = (const float*)d_in[0];
  const float* cnd  = (const float*)d_in[1];
  const float* emb  = (const float*)d_in[2];
  const float* Wlh  = (const float*)d_in[3];
  const float* blh  = (const float*)d_in[4];
  const float* Wih  = (const float*)d_in[5];
  const float* Whh  = (const float*)d_in[6];
  const float* bih  = (const float*)d_in[7];
  const float* bhh  = (const float*)d_in[8];
  const float* Wout = (const float*)d_in[9];
  const float* bout = (const float*)d_in[10];
  float* out = (float*)d_out;

  char* ws = (char*)d_ws;
  size_t off = 0;
  auto alloc = [&](size_t bytes) -> void* {
    off = (off + 255) & ~(size_t)255;
    void* p = ws + off;
    off += bytes;
    return p;
  };
  u16* Whi = (u16*)alloc((size_t)4 * NH * NH * 2);
  u16* Wlo = (u16*)alloc((size_t)4 * NH * NH * 2);
  float* ExW = (float*)alloc((size_t)NV * 4 * NH * 4);
  u16* hhi0 = (u16*)alloc((size_t)NB * NH * 2);
  u16* hhi1 = (u16*)alloc((size_t)NB * NH * 2);
  u16* hlo0 = (u16*)alloc((size_t)NB * NH * 2);
  u16* hlo1 = (u16*)alloc((size_t)NB * NH * 2);
  float* cbuf = (float*)alloc((size_t)NB * NH * 4);
  int* tokb = (int*)alloc((size_t)NB * 4);
  u16* hhi[2] = {hhi0, hhi1};
  u16* hlo[2] = {hlo0, hlo1};

  prep_kernel<<<dim3((4 * NH * NH) / 256), dim3(256), 0, stream>>>(Whh, Whi, Wlo, cbuf, tokb);
  exw_kernel<<<dim3((4 * NH) / 256, NV), dim3(256), 0, stream>>>(emb, Wih, bih, bhh, ExW);
  h0_kernel<<<dim3(NH / 256, NB / 8), dim3(256), 0, stream>>>(z, cnd, Wlh, blh, hhi[0], hlo[0]);

  int p = 0;
  for (int t = 0; t < NT; ++t) {
    gates_cell_kernel<<<dim3(1024), dim3(256), 0, stream>>>(
        Whi, Wlo, hhi[p], hlo[p], ExW, tokb, cbuf, hhi[p ^ 1], hlo[p ^ 1]);
    logits_kernel<<<dim3(NB / 8), dim3(256), 0, stream>>>(
        hhi[p ^ 1], hlo[p ^ 1], Wout, bout, out, tokb, t);
    p ^= 1;
  }
}